// Round 3
// baseline (185.568 us; speedup 1.0000x reference)
//
#include <hip/hip_runtime.h>
#include <hip/hip_cooperative_groups.h>

namespace cg = cooperative_groups;

// VLAD pooling, single cooperative kernel. B=16, S=1024, D=512, KC=12, K=10.
// Harness poison-fills the 256 MiB ws EVERY iter (~43.5 us, unconditional) —
// that is the floor; minimize our own time on top of it:
//  - ONE dispatch (accum + grid.sync + final) instead of two: round-1 data
//    showed single-kernel residual overhead is ~6.6 us vs ~misc gaps with 7
//    dispatches/iter.
//  - 512 blocks x 256 thr = 2 blocks/CU: cross-block wave overlap hides the
//    barrier/vmcnt drains that a 1-block/CU shape exposes.
//  - All 16 feat float4 loads issued up-front, pinned with sched_barrier(0)
//    so hipcc cannot sink them back to their uses (round 2 showed it does).
// Phase 1: block (b,c): 32-pixel chunk, softmax + einsum partials ->
//          part[b][k][c][0:512], asum_part[b][c][k].
// Phase 2 (after grid sync): blocks 0..159 = (b,k): reduce 32 chunks,
//          subtract asum*cluster, L2-normalize, store out.

#define B_   16
#define S_   1024
#define D_   512
#define KC_  12
#define K_   10
#define CH_  32            // chunks per batch (512 blocks total)
#define SCH_ (S_ / CH_)    // 32 pixels per chunk
#define NT   256
#define NPAR 2             // s-parities: par = tid>>7, wave-uniform
#define NPX  (SCH_ / NPAR) // 16 pixels per thread

__global__ __launch_bounds__(NT, 2) void vlad_all(
    const float* __restrict__ feat, const float* __restrict__ score,
    const float* __restrict__ cluster, float* __restrict__ out,
    float* __restrict__ part, float* __restrict__ asum_part)
{
    const int bid = blockIdx.x;
    const int b   = bid >> 5;          // CH_=32 chunks per batch
    const int c   = bid & (CH_ - 1);
    const int s0  = c * SCH_;
    const int tid = threadIdx.x;
    const int par = tid >> 7;          // 0..1, wave-uniform
    const int col = tid & 127;         // float4 column in D

    __shared__ float  As[SCH_][KC_];   // 1.5 KB softmax weights
    __shared__ float4 red[K_][128];    // 20 KB parity-1 partials
    __shared__ float  wsum[4];

    // ---- phase 1a: issue score loads (tid<32), then ALL 16 feat loads ----
    float4 w0, w1, w2;
    if (tid < SCH_) {
        const float4* sp = (const float4*)(score + (size_t)(b * S_ + s0 + tid) * KC_);
        w0 = sp[0]; w1 = sp[1]; w2 = sp[2];
    }
    const float4* fp = (const float4*)(feat + (size_t)(b * S_ + s0) * D_) + col;
    float4 v[NPX];
    #pragma unroll
    for (int i = 0; i < NPX; i++)
        v[i] = fp[(size_t)(NPAR * i + par) * (D_ / 4)];
    __builtin_amdgcn_sched_barrier(0);   // do NOT sink the loads below this

    // ---- phase 1b: softmax for this chunk's 32 pixels ----
    if (tid < SCH_) {
        float x[KC_] = {w0.x, w0.y, w0.z, w0.w, w1.x, w1.y, w1.z, w1.w,
                        w2.x, w2.y, w2.z, w2.w};
        float m = x[0];
        #pragma unroll
        for (int k = 1; k < KC_; k++) m = fmaxf(m, x[k]);
        float sum = 0.f;
        #pragma unroll
        for (int k = 0; k < KC_; k++) { x[k] = __expf(x[k] - m); sum += x[k]; }
        const float inv = 1.0f / sum;
        #pragma unroll
        for (int k = 0; k < KC_; k++) As[tid][k] = x[k] * inv;
    }
    __syncthreads();

    if (tid < K_) {
        float s = 0.f;
        #pragma unroll
        for (int p = 0; p < SCH_; p++) s += As[p][tid];
        asum_part[(b * CH_ + c) * K_ + tid] = s;
    }

    // ---- phase 1c: accumulate the 16 prefetched pixels over 10 clusters ----
    float acc[K_][4];
    #pragma unroll
    for (int k = 0; k < K_; k++)
        acc[k][0] = acc[k][1] = acc[k][2] = acc[k][3] = 0.f;

    #pragma unroll
    for (int i = 0; i < NPX; i++) {
        const int s = NPAR * i + par;
        const float4 a0 = *(const float4*)(&As[s][0]);   // uniform broadcast
        const float4 a1 = *(const float4*)(&As[s][4]);
        const float2 a2 = *(const float2*)(&As[s][8]);
        const float a[K_] = {a0.x, a0.y, a0.z, a0.w, a1.x, a1.y, a1.z, a1.w,
                             a2.x, a2.y};
        #pragma unroll
        for (int k = 0; k < K_; k++) {
            acc[k][0] += a[k] * v[i].x;
            acc[k][1] += a[k] * v[i].y;
            acc[k][2] += a[k] * v[i].z;
            acc[k][3] += a[k] * v[i].w;
        }
    }

    // ---- phase 1d: parity combine (par 1 -> par 0), store partials ----
    if (par) {
        #pragma unroll
        for (int k = 0; k < K_; k++)
            red[k][col] = make_float4(acc[k][0], acc[k][1], acc[k][2], acc[k][3]);
    }
    __syncthreads();
    if (!par) {
        float* pp = part + (((size_t)(b * K_) * CH_ + c) * D_) + col * 4;
        #pragma unroll
        for (int k = 0; k < K_; k++) {
            const float4 t = red[k][col];
            *(float4*)(pp + (size_t)k * CH_ * D_) =
                make_float4(acc[k][0] + t.x, acc[k][1] + t.y,
                            acc[k][2] + t.z, acc[k][3] + t.w);
        }
    }

    // ---- grid-wide barrier: part/asum_part visible to all XCDs ----
    __threadfence();
    cg::this_grid().sync();

    // ---- phase 2: blocks 0..159 reduce + normalize one (b,k) row ----
    if (bid < B_ * K_) {
        const int b2 = bid / K_;
        const int k2 = bid % K_;
        const int d  = tid * 2;
        const int lane = tid & 63, wave = tid >> 6;

        const float* base = part + ((size_t)(b2 * K_ + k2) * CH_) * D_ + d;
        float2 pv[CH_];
        #pragma unroll
        for (int cc = 0; cc < CH_; cc++)
            pv[cc] = *(const float2*)(base + (size_t)cc * D_);
        __builtin_amdgcn_sched_barrier(0);

        float asv = 0.f;
        #pragma unroll
        for (int cc = 0; cc < CH_; cc++)
            asv += asum_part[(b2 * CH_ + cc) * K_ + k2];

        float r0 = 0.f, r1 = 0.f;
        #pragma unroll
        for (int cc = 0; cc < CH_; cc++) { r0 += pv[cc].x; r1 += pv[cc].y; }

        const float2 cv = *(const float2*)(cluster + (size_t)k2 * D_ + d);
        r0 -= asv * cv.x;
        r1 -= asv * cv.y;

        float sq = r0 * r0 + r1 * r1;
        #pragma unroll
        for (int off = 32; off > 0; off >>= 1) sq += __shfl_down(sq, off, 64);
        __syncthreads();                 // red/As dead; reuse barrier for wsum
        if (lane == 0) wsum[wave] = sq;
        __syncthreads();
        const float tot   = wsum[0] + wsum[1] + wsum[2] + wsum[3];
        const float scale = rsqrtf(fmaxf(tot, 1e-12f));

        *(float2*)(out + (size_t)(b2 * K_ + k2) * D_ + d) =
            make_float2(r0 * scale, r1 * scale);
    }
}

extern "C" void kernel_launch(void* const* d_in, const int* in_sizes, int n_in,
                              void* d_out, int out_size, void* d_ws, size_t ws_size,
                              hipStream_t stream) {
    const float* feat    = (const float*)d_in[0];
    const float* score   = (const float*)d_in[1];
    const float* cluster = (const float*)d_in[2];
    float* out = (float*)d_out;

    float* part      = (float*)d_ws;                        // B*K*CH*D fp32
    float* asum_part = part + (size_t)B_ * K_ * CH_ * D_;   // B*CH*K fp32

    void* args[] = {(void*)&feat, (void*)&score, (void*)&cluster,
                    (void*)&out,  (void*)&part,  (void*)&asum_part};
    hipLaunchCooperativeKernel((const void*)vlad_all,
                               dim3(B_ * CH_), dim3(NT), args, 0, stream);
}

// Round 4
// 85.147 us; speedup vs baseline: 2.1794x; 2.1794x over previous
//
#include <hip/hip_runtime.h>

// VLAD pooling: B=16, S=1024, D=512, KC=12, K=10, fp32.
// Fixed costs per iter: 256 MiB ws poison fill ~43.5 us (unconditional,
// stream-ordered — measured r1) + ~2-3 us per dispatch gap.
// r3 lesson: grid.sync costs ~60 us -> two plain kernels.
// r2/r3 lesson: hipcc DISCARDS source-level register prefetch (VGPR=64 with
// v[16] float4 in source) -> use __builtin_amdgcn_global_load_lds, which it
// honors, to build the deep pipeline.
// K1: 512 blocks (b, c) x 256 thr, 2 blocks/CU. Score loads first, then 64x
//     1KB async feat->LDS stages (16/wave); softmax overlaps staging (vmcnt
//     FIFO: score oldest). After one barrier: pure LDS+VALU accumulate,
//     each thread owns a float2 column over all 32 pixels (no parity pass).
// K2: 160 blocks (b,k) x 256 thr: reduce 32 chunks, subtract asum*cluster,
//     L2-normalize.

#define B_   16
#define S_   1024
#define D_   512
#define KC_  12
#define K_   10
#define CH_  32            // chunks per batch
#define SCH_ (S_ / CH_)    // 32 pixels per chunk
#define NT1  256

__global__ __launch_bounds__(NT1, 2) void vlad_accum(
    const float* __restrict__ feat, const float* __restrict__ score,
    float* __restrict__ part, float* __restrict__ asum_part)
{
    const int bid  = blockIdx.x;
    const int b    = bid >> 5;          // CH_ = 32
    const int c    = bid & (CH_ - 1);
    const int s0   = c * SCH_;
    const int tid  = threadIdx.x;
    const int wave = tid >> 6;
    const int lane = tid & 63;

    __shared__ float fl[SCH_][D_];      // 64 KB staged feat chunk
    __shared__ float As[SCH_][KC_];     // 1.5 KB softmax weights

    // ---- 1. score loads FIRST (oldest in vmcnt FIFO) ----
    float4 w0, w1, w2;
    if (tid < SCH_) {
        const float4* sp = (const float4*)(score + (size_t)(b * S_ + s0 + tid) * KC_);
        w0 = sp[0]; w1 = sp[1]; w2 = sp[2];
    }

    // ---- 2. async-stage the 64 KB feat chunk: 16 x 1KB per wave ----
    {
        const float* gbase = feat + (size_t)(b * S_ + s0) * D_;
        #pragma unroll
        for (int j = 0; j < 16; j++) {
            const int seg = wave * 16 + j;               // 0..63
            const float* gp = gbase + seg * 256 + lane * 4;  // per-lane 16B
            const float* lp = &fl[0][0] + seg * 256;         // wave-uniform
            __builtin_amdgcn_global_load_lds(
                (const __attribute__((address_space(1))) void*)gp,
                (__attribute__((address_space(3))) void*)lp,
                16, 0, 0);
        }
    }

    // ---- 3. softmax (waits vmcnt(16): score done, staging in flight) ----
    if (tid < SCH_) {
        float x[KC_] = {w0.x, w0.y, w0.z, w0.w, w1.x, w1.y, w1.z, w1.w,
                        w2.x, w2.y, w2.z, w2.w};
        float m = x[0];
        #pragma unroll
        for (int k = 1; k < KC_; k++) m = fmaxf(m, x[k]);
        float sum = 0.f;
        #pragma unroll
        for (int k = 0; k < KC_; k++) { x[k] = __expf(x[k] - m); sum += x[k]; }
        const float inv = 1.0f / sum;
        #pragma unroll
        for (int k = 0; k < KC_; k++) x[k] *= inv;
        *(float4*)&As[tid][0] = make_float4(x[0], x[1], x[2],  x[3]);
        *(float4*)&As[tid][4] = make_float4(x[4], x[5], x[6],  x[7]);
        *(float4*)&As[tid][8] = make_float4(x[8], x[9], x[10], x[11]);
        // asum over the 32 pixels (lanes 0..31 of wave 0) via shuffle
        #pragma unroll
        for (int k = 0; k < K_; k++) {
            float r = x[k];
            r += __shfl_down(r, 16, 32);
            r += __shfl_down(r, 8, 32);
            r += __shfl_down(r, 4, 32);
            r += __shfl_down(r, 2, 32);
            r += __shfl_down(r, 1, 32);
            if (tid == 0) asum_part[(b * CH_ + c) * K_ + k] = r;
        }
    }
    __syncthreads();    // drains vmcnt(0): staged feat + As visible

    // ---- 4. accumulate: each thread owns float2 column d0, all 32 pixels ----
    const int d0 = tid * 2;
    float acc[K_][2];
    #pragma unroll
    for (int k = 0; k < K_; k++) acc[k][0] = acc[k][1] = 0.f;

    #pragma unroll 8
    for (int s = 0; s < SCH_; s++) {
        const float2 v  = *(const float2*)&fl[s][d0];
        const float4 a0 = *(const float4*)&As[s][0];   // uniform broadcasts
        const float4 a1 = *(const float4*)&As[s][4];
        const float2 a2 = *(const float2*)&As[s][8];
        const float a[K_] = {a0.x, a0.y, a0.z, a0.w, a1.x, a1.y, a1.z, a1.w,
                             a2.x, a2.y};
        #pragma unroll
        for (int k = 0; k < K_; k++) {
            acc[k][0] += a[k] * v.x;
            acc[k][1] += a[k] * v.y;
        }
    }

    // ---- 5. store partials: part[b][k][c][d] ----
    float* pp = part + (((size_t)(b * K_) * CH_ + c) * D_) + d0;
    #pragma unroll
    for (int k = 0; k < K_; k++)
        *(float2*)(pp + (size_t)k * CH_ * D_) = make_float2(acc[k][0], acc[k][1]);
}

// One block per (b,k): reduce 32 chunks, subtract asum*cluster, L2-normalize.
__global__ __launch_bounds__(256) void vlad_final(
    const float* __restrict__ part, const float* __restrict__ asum_part,
    const float* __restrict__ cluster, float* __restrict__ out)
{
    const int b   = blockIdx.x / K_;
    const int k   = blockIdx.x % K_;
    const int tid = threadIdx.x;
    const int d   = tid * 2;

    const float* base = part + ((size_t)(b * K_ + k) * CH_) * D_ + d;
    float s0 = 0.f, s1 = 0.f;
    #pragma unroll
    for (int c = 0; c < CH_; c++) {
        const float2 v = *(const float2*)(base + (size_t)c * D_);
        s0 += v.x; s1 += v.y;
    }
    float asv = 0.f;
    #pragma unroll
    for (int c = 0; c < CH_; c++) asv += asum_part[(b * CH_ + c) * K_ + k];

    const float2 cv = *(const float2*)(cluster + (size_t)k * D_ + d);
    const float r0 = s0 - asv * cv.x;
    const float r1 = s1 - asv * cv.y;

    float sq = r0 * r0 + r1 * r1;
    #pragma unroll
    for (int off = 32; off > 0; off >>= 1) sq += __shfl_down(sq, off, 64);
    __shared__ float wsum[4];
    if ((tid & 63) == 0) wsum[tid >> 6] = sq;
    __syncthreads();
    const float tot   = wsum[0] + wsum[1] + wsum[2] + wsum[3];
    const float scale = rsqrtf(fmaxf(tot, 1e-12f));

    *(float2*)(out + (size_t)(b * K_ + k) * D_ + d) =
        make_float2(r0 * scale, r1 * scale);
}

extern "C" void kernel_launch(void* const* d_in, const int* in_sizes, int n_in,
                              void* d_out, int out_size, void* d_ws, size_t ws_size,
                              hipStream_t stream) {
    const float* feat    = (const float*)d_in[0];
    const float* score   = (const float*)d_in[1];
    const float* cluster = (const float*)d_in[2];
    float* out = (float*)d_out;

    float* part      = (float*)d_ws;                        // B*K*CH*D fp32
    float* asum_part = part + (size_t)B_ * K_ * CH_ * D_;   // B*CH*K fp32

    vlad_accum<<<B_ * CH_, NT1, 0, stream>>>(feat, score, part, asum_part);
    vlad_final<<<B_ * K_, 256, 0, stream>>>(part, asum_part, cluster, out);
}